// Round 8
// baseline (774.348 us; speedup 1.0000x reference)
//
#include <hip/hip_runtime.h>
#include <stdint.h>
#include <math.h>

typedef __attribute__((ext_vector_type(8))) short s8v;
typedef __attribute__((ext_vector_type(4))) short s4v;
typedef __attribute__((ext_vector_type(4))) float f4v;

#define DEV static __device__ __forceinline__

DEV short f2bf(float f) {
  uint32_t u = __builtin_bit_cast(uint32_t, f);
  u += 0x7FFFu + ((u >> 16) & 1u);   // round-to-nearest-even
  return (short)(u >> 16);
}
DEV float bf2f(short s) {
  uint32_t u = ((uint32_t)(uint16_t)s) << 16;
  return __builtin_bit_cast(float, u);
}

#define GLD16(g, l) __builtin_amdgcn_global_load_lds( \
    (const __attribute__((address_space(1))) void*)(g), \
    (__attribute__((address_space(3))) void*)(l), 16, 0, 0)

// tail-work descriptor: up to 7 f32[R,C] -> bf16[C,R] transposes run by surplus blocks
struct TailWT {
  const float* src[7]; short* dst[7];
  int R[7], C[7], tiles[7];
};

// ================= 128x128 GEMM (m97 structure) for small/odd/batched shapes =========
__global__ __launch_bounds__(256) void gemm_bt(
    const short* __restrict__ A, const short* __restrict__ B,
    float* Cf, short* Cb,
    const float* __restrict__ bias, const float* resid,
    int M, int N, int K, int lda, int ldb, int ldc,
    long long sAo, long long sAi, long long sBo, long long sBi,
    long long sCo, long long sCi, float alpha, int relu)
{
  __shared__ __align__(16) short lA[128*32];
  __shared__ __align__(16) short lB[128*32];
  const int z = blockIdx.z, zo = z >> 3, zi = z & 7;
  const short* Ab = A + zo*sAo + zi*sAi;
  const short* Bb = B + zo*sBo + zi*sBi;
  const long long cOff = zo*sCo + zi*sCi;

  const int m0 = blockIdx.y*128, n0 = blockIdx.x*128;
  const int tid = threadIdx.x, lane = tid & 63, wv = tid >> 6;
  const int wm = (wv >> 1)*64, wn = (wv & 1)*64;
  const int fr = lane & 15, fq = lane >> 4;

  f4v acc[4][4] = {};

  const int rA0 = min(m0 + (tid >> 2), M - 1);
  const int rA1 = min(m0 + 64 + (tid >> 2), M - 1);
  const int rB0 = min(n0 + (tid >> 2), N - 1);
  const int rB1 = min(n0 + 64 + (tid >> 2), N - 1);
  const int pc = (tid & 3) * 8;
  const short* gA0 = Ab + (size_t)rA0*lda + pc;
  const short* gA1 = Ab + (size_t)rA1*lda + pc;
  const short* gB0 = Bb + (size_t)rB0*ldb + pc;
  const short* gB1 = Bb + (size_t)rB1*ldb + pc;
  short* dA0 = lA + (wv*64)*8;
  short* dA1 = lA + (256 + wv*64)*8;
  short* dB0 = lB + (wv*64)*8;
  short* dB1 = lB + (256 + wv*64)*8;

  for (int k0 = 0; k0 < K; k0 += 32) {
    GLD16(gA0 + k0, dA0);
    GLD16(gA1 + k0, dA1);
    GLD16(gB0 + k0, dB0);
    GLD16(gB1 + k0, dB1);
    __syncthreads();
    s8v af[4], bg[4];
#pragma unroll
    for (int i = 0; i < 4; i++) {
      af[i] = *(const s8v*)&lA[(wm + i*16 + fr)*32 + fq*8];
      bg[i] = *(const s8v*)&lB[(wn + i*16 + fr)*32 + fq*8];
    }
#pragma unroll
    for (int mi = 0; mi < 4; mi++)
#pragma unroll
      for (int ni = 0; ni < 4; ni++)
        acc[mi][ni] = __builtin_amdgcn_mfma_f32_16x16x32_bf16(af[mi], bg[ni], acc[mi][ni], 0, 0, 0);
    __syncthreads();
  }

#pragma unroll
  for (int mi = 0; mi < 4; mi++) {
    const int row = m0 + wm + mi*16 + fq*4;
#pragma unroll
    for (int ni = 0; ni < 4; ni++) {
      const int col = n0 + wn + ni*16 + fr;
      if (col >= N) continue;
      const float bv = bias ? bias[col] : 0.f;
#pragma unroll
      for (int r = 0; r < 4; r++) {
        if (row + r >= M) continue;
        float v = acc[mi][ni][r] * alpha + bv;
        const long long idx = cOff + (long long)(row + r)*ldc + col;
        if (resid) v += resid[idx];
        if (relu) v = fmaxf(v, 0.f);
        if (Cf) Cf[idx] = v;
        if (Cb) Cb[idx] = f2bf(v);
      }
    }
  }
}

// ================= 256x256 8-phase GEMM (r6 single-barrier schedule) ======
// waits only at ph4/ph8 (vmcnt(6)); stage ring 1 phase after last read.
// Surplus blocks (bid >= nb012) run TailWT transposes on otherwise-idle CUs.
#define ST_A(buf, ks, tt) do { const int ko = ((tt)<<6) + ((ks)<<5); \
    GLD16(gA0 + ko, ldA + ((buf)*2+(ks))*8192); \
    GLD16(gA1 + ko, ldA + ((buf)*2+(ks))*8192 + 4096); } while(0)
#define ST_B(buf, ks, tt) do { const int ko = ((tt)<<6) + ((ks)<<5); \
    GLD16(gB0 + ko, ldB + ((buf)*2+(ks))*8192); \
    GLD16(gB1 + ko, ldB + ((buf)*2+(ks))*8192 + 4096); } while(0)

#define PH256(buf, ks, mig, READB, DOWAIT, ...) do { \
    s8v av[4]; \
    const int rb = ((buf)*2+(ks))*8192; \
    _Pragma("unroll") for (int q2 = 0; q2 < 4; q2++) av[q2] = *(const s8v*)&smem[rb + aoff[(mig)*4+q2]]; \
    if (READB) { _Pragma("unroll") for (int q2 = 0; q2 < 4; q2++) bv[q2] = *(const s8v*)&smem[32768 + rb + boff[q2]]; } \
    __VA_ARGS__; \
    if (DOWAIT == 1) asm volatile("s_waitcnt vmcnt(6)" ::: "memory"); \
    if (DOWAIT == 2) asm volatile("s_waitcnt vmcnt(0)" ::: "memory"); \
    __builtin_amdgcn_s_barrier(); \
    asm volatile("s_waitcnt lgkmcnt(0)" ::: "memory"); \
    __builtin_amdgcn_s_setprio(1); \
    _Pragma("unroll") for (int q2 = 0; q2 < 4; q2++) \
      _Pragma("unroll") for (int u2 = 0; u2 < 4; u2++) \
        acc[(mig)*4+q2][u2] = __builtin_amdgcn_mfma_f32_16x16x32_bf16(av[q2], bv[u2], acc[(mig)*4+q2][u2], 0, 0, 0); \
    __builtin_amdgcn_s_setprio(0); \
  } while(0)

__global__ __launch_bounds__(512, 2) void gemm256(
    const short* __restrict__ A0p, const short* __restrict__ B0p,
    float* C0f, short* C0b, const float* __restrict__ bias0, const float* res0,
    int nb0, int nbm0, int N0, float al0,
    const short* __restrict__ A1p, const short* __restrict__ B1p,
    float* C1f, short* C1b, const float* __restrict__ bias1, const float* res1,
    int nb01, int nbm1, int N1, float al1,
    const short* __restrict__ A2p, const short* __restrict__ B2p,
    float* C2f, short* C2b, const float* __restrict__ bias2, const float* res2,
    int nbm2, int N2, float al2,
    int nb012, TailWT tw,
    int K, int relu)
{
  __shared__ __align__(16) short smem[65536];   // 128 KiB
  const int total = gridDim.x;
  int bid = blockIdx.x;
  if ((total & 7) == 0) bid = (bid & 7)*(total >> 3) + (bid >> 3);   // bijective XCD swizzle
  const int t = threadIdx.x;

  if (bid >= nb012) {
    // ---- tail path: f32 [R,C] -> bf16 [C,R] transposes, 2 tiles per iteration ----
    const int ntb = total - nb012;
    const int sub = t >> 8, tt2 = t & 255;
    const int tx = tt2 & 31, ty2 = tt2 >> 5;
    int pre[7], NT = 0;
#pragma unroll
    for (int o = 0; o < 7; o++) { pre[o] = NT; NT += tw.tiles[o]; }
    float* tl = (float*)smem + sub*(32*33);
    for (int base = (bid - nb012)*2; base < NT; base += ntb*2) {
      const int my = base + sub;
      int op = 6;
#pragma unroll
      for (int o = 6; o >= 1; o--) if (my < pre[o]) op = o - 1;
      const int loc = my - pre[op];
      const int Cd = tw.C[op], Rd = tw.R[op], ncx = Cd >> 5;
      const int cx = (loc % ncx) << 5, ry = (loc / ncx) << 5;
      if (my < NT) {
        const float* s = tw.src[op];
#pragma unroll
        for (int k2 = 0; k2 < 4; k2++)
          tl[(ty2 + k2*8)*33 + tx] = s[(size_t)(ry + ty2 + k2*8)*Cd + cx + tx];
      }
      __syncthreads();
      if (my < NT) {
        short* d2 = tw.dst[op];
#pragma unroll
        for (int k2 = 0; k2 < 4; k2++)
          d2[(size_t)(cx + ty2 + k2*8)*Rd + ry + tx] = f2bf(tl[tx*33 + ty2 + k2*8]);
      }
      __syncthreads();
    }
    return;
  }

  const short* A; const short* B; float* Cf; short* Cb; const float* bias; const float* resid;
  int tile, nbm, N; float alpha;
  if (bid < nb0)       { A = A0p; B = B0p; Cf = C0f; Cb = C0b; bias = bias0; resid = res0;
                         tile = bid; nbm = nbm0; N = N0; alpha = al0; }
  else if (bid < nb01) { A = A1p; B = B1p; Cf = C1f; Cb = C1b; bias = bias1; resid = res1;
                         tile = bid - nb0; nbm = nbm1; N = N1; alpha = al1; }
  else                 { A = A2p; B = B2p; Cf = C2f; Cb = C2b; bias = bias2; resid = res2;
                         tile = bid - nb01; nbm = nbm2; N = N2; alpha = al2; }
  const int bm = tile % nbm, bn = tile / nbm;   // col-major: consecutive tiles share B panel
  const int m0 = bm << 8, n0 = bn << 8;
  const int lane = t & 63, w = t >> 6;
  const int wm = w >> 2, wn = w & 3;
  const int fr = lane & 15, fq = lane >> 4;
  const int ntk = K >> 6;                        // requires K % 128 == 0, K >= 256

  // staging: region = 256 rows x 32 cols; pre-swizzled global source
  const int r0 = t >> 2, r1 = 128 + (t >> 2), gsw = t & 3;
  const int cs0 = (gsw ^ ((r0 >> 1) & 3)) << 3;
  const int cs1 = (gsw ^ ((r1 >> 1) & 3)) << 3;
  const short* gA0 = A + (size_t)(m0 + r0)*K + cs0;
  const short* gA1 = A + (size_t)(m0 + r1)*K + cs1;
  const short* gB0 = B + (size_t)(n0 + r0)*K + cs0;
  const short* gB1 = B + (size_t)(n0 + r1)*K + cs1;
  short* const ldA = smem + w*512;
  short* const ldB = smem + 32768 + w*512;

  // ds_read fragment offsets (swizzled)
  int aoff[8], boff[4];
#pragma unroll
  for (int mi = 0; mi < 8; mi++) { const int r = wm*128 + mi*16 + fr; aoff[mi] = r*32 + ((fq ^ ((r >> 1) & 3)) << 3); }
#pragma unroll
  for (int ni = 0; ni < 4; ni++) { const int r = wn*64 + ni*16 + fr; boff[ni] = r*32 + ((fq ^ ((r >> 1) & 3)) << 3); }

  f4v acc[8][4] = {};
  s8v bv[4];

  // prologue: buf0 (t0) fully + buf1 (t1) B10,A10,B11 -> 7 stages, 14 loads.
  ST_A(0,0,0); ST_B(0,0,0); ST_A(0,1,0); ST_B(0,1,0);
  ST_B(1,0,1); ST_A(1,0,1); ST_B(1,1,1);
  asm volatile("s_waitcnt vmcnt(6)" ::: "memory");
  __builtin_amdgcn_s_barrier();
  asm volatile("" ::: "memory");

  for (int it = 0, nit = (ntk >> 1) - 1; it < nit; ++it) {
    const int t1 = 2*it + 1, t2 = 2*it + 2, t3 = 2*it + 3;
    PH256(0,0,0, 1,0, ST_A(1,1,t1));   // ph1
    PH256(0,0,1, 0,0, ST_B(0,0,t2));   // ph2
    PH256(0,1,0, 1,0, ST_A(0,0,t2));   // ph3
    PH256(0,1,1, 0,1, ST_B(0,1,t2));   // ph4 + vmcnt(6)
    PH256(1,0,0, 1,0, ST_A(0,1,t2));   // ph5
    PH256(1,0,1, 0,0, ST_B(1,0,t3));   // ph6
    PH256(1,1,0, 1,0, ST_A(1,0,t3));   // ph7
    PH256(1,1,1, 0,1, ST_B(1,1,t3));   // ph8 + vmcnt(6)
  }
  // peeled final iteration: only A11 left to stage; drain at ph4
  PH256(0,0,0, 1,0, ST_A(1,1,ntk-1));
  PH256(0,0,1, 0,0, );
  PH256(0,1,0, 1,0, );
  PH256(0,1,1, 0,2, );                 // vmcnt(0): buf1 fully resident
  PH256(1,0,0, 1,0, );
  PH256(1,0,1, 0,0, );
  PH256(1,1,0, 1,0, );
  PH256(1,1,1, 0,0, );

  // epilogue
#pragma unroll
  for (int mi = 0; mi < 8; mi++) {
    const int row = m0 + wm*128 + mi*16 + fq*4;
#pragma unroll
    for (int ni = 0; ni < 4; ni++) {
      const int col = n0 + wn*64 + ni*16 + fr;
      const float bvv = bias ? bias[col] : 0.f;
#pragma unroll
      for (int r = 0; r < 4; r++) {
        float v = acc[mi][ni][r]*alpha + bvv;
        const size_t idx = (size_t)(row + r)*N + col;
        if (resid) v += resid[idx];
        if (relu) v = fmaxf(v, 0.f);
        if (Cf) Cf[idx] = v;
        else Cb[idx] = f2bf(v);
      }
    }
  }
}

// ============ weight transpose+convert: src f32 [R,C] -> dst bf16 [C,R] ============
__global__ __launch_bounds__(256) void wtrans(const float* __restrict__ src,
                                              short* __restrict__ dst, int R, int C)
{
  __shared__ float t[32][33];
  const int c0 = blockIdx.x*32, r0 = blockIdx.y*32;
  const int tx = threadIdx.x, ty = threadIdx.y;
#pragma unroll
  for (int k = 0; k < 4; k++)
    t[ty + k*8][tx] = src[(size_t)(r0 + ty + k*8)*C + c0 + tx];
  __syncthreads();
#pragma unroll
  for (int k = 0; k < 4; k++)
    dst[(size_t)(c0 + ty + k*8)*R + r0 + tx] = f2bf(t[tx][ty + k*8]);
}

// ============ batched bf16 transpose ============
__global__ __launch_bounds__(256) void btrans(const short* __restrict__ src, short* __restrict__ dst,
    int ls, int ld_, long long sSo, long long sSi, long long sDo, long long sDi)
{
  __shared__ short t[32][33];
  const int z = blockIdx.z;
  const short* S = src + (z>>3)*sSo + (z&7)*sSi;
  short* D = dst + (z>>3)*sDo + (z&7)*sDi;
  const int c0 = blockIdx.x*32, r0 = blockIdx.y*32;
  const int tx = threadIdx.x, ty = threadIdx.y;
#pragma unroll
  for (int k = 0; k < 4; k++)
    t[ty + k*8][tx] = S[(size_t)(r0 + ty + k*8)*ls + c0 + tx];
  __syncthreads();
#pragma unroll
  for (int k = 0; k < 4; k++)
    D[(size_t)(c0 + ty + k*8)*ld_ + r0 + tx] = t[tx][ty + k*8];
}

// ============ f32 -> bf16 convert ============
__global__ __launch_bounds__(256) void conv_bf(const float* __restrict__ src,
                                               short* __restrict__ dst, long long n)
{
  const long long i = ((long long)blockIdx.x*256 + threadIdx.x)*4;
  if (i >= n) return;
  const float4 v = *(const float4*)(src + i);
  s4v o = { f2bf(v.x), f2bf(v.y), f2bf(v.z), f2bf(v.w) };
  *(s4v*)(dst + i) = o;
}

// ============ LayerNorm over 1536 cols, f32 in -> bf16 out ============
__global__ __launch_bounds__(256) void ln_k(const float* __restrict__ in,
    const float* __restrict__ gam, const float* __restrict__ bet, short* __restrict__ out)
{
  const long long row = blockIdx.x;
  const float* r = in + row*1536;
  const int tid = threadIdx.x;
  float v[6], s = 0.f, s2 = 0.f;
#pragma unroll
  for (int i = 0; i < 6; i++) { v[i] = r[tid + i*256]; s += v[i]; s2 += v[i]*v[i]; }
  for (int m = 1; m < 64; m <<= 1) { s += __shfl_xor(s, m); s2 += __shfl_xor(s2, m); }
  __shared__ float rs[4], rs2[4];
  if ((tid & 63) == 0) { rs[tid>>6] = s; rs2[tid>>6] = s2; }
  __syncthreads();
  s = rs[0]+rs[1]+rs[2]+rs[3]; s2 = rs2[0]+rs2[1]+rs2[2]+rs2[3];
  const float mu  = s * (1.f/1536.f);
  const float var = s2 * (1.f/1536.f) - mu*mu;
  const float inv = rsqrtf(var + 1e-5f);
  short* o = out + row*1536;
#pragma unroll
  for (int i = 0; i < 6; i++) { int c = tid + i*256; o[c] = f2bf((v[i]-mu)*inv*gam[c] + bet[c]); }
}

// ============ positional features: out bf16 [2047][192] ============
__global__ __launch_bounds__(64) void posemb(short* __restrict__ out)
{
  const int i = blockIdx.x;
  const int j = threadIdx.x;
  const float dist = (float)(i - 1023);
  const float absd = fabsf(dist);
  float fe = 0.f, fc = 0.f, prob = 0.f;
  if (j < 32) {
    const float hl = exp2f(3.f + 7.f*(float)j/31.f);
    fe = expf(-0.6931471805599453f/hl * absd);
    const float width = exp2f((float)(j+1)) - 1.f;
    fc = (width > absd) ? 1.f : 0.f;
    const float m = 32.f*(float)(j+1);
    const float conc = (m/16.f)*(m/16.f);
    const float rate = m/256.f;
    const float logp = (absd > 0.f ? (conc-1.f)*logf(absd) : -INFINITY) - rate*absd;
    const float logn = lgammaf(conc) - conc*logf(rate);
    prob = expf(logp - logn) + 1e-8f;
  }
  float mx = prob;
  for (int m = 1; m < 32; m <<= 1) mx = fmaxf(mx, __shfl_xor(mx, m));
  if (j < 32) {
    const float fg = prob / mx;
    const float sg = dist > 0.f ? 1.f : (dist < 0.f ? -1.f : 0.f);
    const size_t base = (size_t)i*192;
    out[base + j]       = f2bf(fe);
    out[base + 32 + j]  = f2bf(fc);
    out[base + 64 + j]  = f2bf(fg);
    out[base + 96 + j]  = f2bf(sg*fe);
    out[base + 128 + j] = f2bf(sg*fc);
    out[base + 160 + j] = f2bf(sg*fg);
  }
}

// ============ rel bias table: T[h][n] = dot64(rpb[h], relq[n,h*64:]) ============
__global__ __launch_bounds__(256) void relbias_k(const float* __restrict__ rpb,
    const short* __restrict__ relq, float* __restrict__ T)
{
  const int n = blockIdx.x;
  const int tid = threadIdx.x;
  const int h = tid >> 5, l = tid & 31;
  const int d = l*2;
  float s = rpb[h*64+d]   * bf2f(relq[(size_t)n*512 + h*64 + d])
          + rpb[h*64+d+1] * bf2f(relq[(size_t)n*512 + h*64 + d+1]);
  for (int m = 1; m < 32; m <<= 1) s += __shfl_xor(s, m);
  if (l == 0) T[h*2047 + n] = s;
}

// ============ fused scores: L[z,i,j] = q·k^T + 0.125*(k@relq^T)[j,63+il-jl] + T[h,n] =====
__global__ __launch_bounds__(256) void scores_k(
    const short* __restrict__ qb, const short* __restrict__ kb,
    const short* __restrict__ relq, const float* __restrict__ T,
    float* __restrict__ L)
{
  __shared__ __align__(16) short smem[21504];
  short* kt  = smem;                 // 64*72
  short* qt  = smem + 4608;          // 64*72
  short* rqt = smem + 4608;          // 128*72 (over qt)
  float* P   = (float*)(smem + 4608);// 64*132 f32 (over rqt)

  const int z = blockIdx.z, b = z >> 3, h = z & 7;
  const int j0 = blockIdx.x*64, i0 = blockIdx.y*64;
  const int tid = threadIdx.x, lane = tid & 63, wv = tid >> 6;
  const int fr = lane & 15, fq = lane >> 4;

  {
    const short* kg = kb + (size_t)(b*768  + j0)*512 + h*64;
    const short* qg = qb + (size_t)(b*1024 + i0)*512 + h*64;
    for (int c = tid; c < 512; c += 256) {
      const int r = c >> 3, ch = (c & 7)*8;
      *(s8v*)&kt[r*72 + ch] = *(const s8v*)&kg[(size_t)r*512 + ch];
      *(s8v*)&qt[r*72 + ch] = *(const s8v*)&qg[(size_t)r*512 + ch];
    }
  }
  __syncthreads();

  const int wi = (wv & 1)*32, wj = (wv >> 1)*32;
  f4v c2[2][2] = {};
#pragma unroll
  for (int ks = 0; ks < 2; ks++) {
    s8v aq[2], bk[2];
#pragma unroll
    for (int mi = 0; mi < 2; mi++) aq[mi] = *(const s8v*)&qt[(wi + mi*16 + fr)*72 + ks*32 + fq*8];
#pragma unroll
    for (int ni = 0; ni < 2; ni++) bk[ni] = *(const s8v*)&kt[(wj + ni*16 + fr)*72 + ks*32 + fq*8];
#pragma unroll
    for (int mi = 0; mi < 2; mi++)
#pragma unroll
      for (int ni = 0; ni < 2; ni++)
        c2[mi][ni] = __builtin_amdgcn_mfma_f32_16x16x32_bf16(aq[mi], bk[ni], c2[mi][ni], 0, 0, 0);
  }
  __syncthreads();

  const int nbase = 704 + i0 - j0;
  {
    const short* rg = relq + (size_t)nbase*512 + h*64;
    for (int c = tid; c < 1024; c += 256) {
      const int r = c >> 3, ch = (c & 7)*8;
      *(s8v*)&rqt[r*72 + ch] = *(const s8v*)&rg[(size_t)r*512 + ch];
    }
  }
  __syncthreads();

  const int wj2 = (wv & 1)*32, wn2 = (wv >> 1)*64;
  f4v pr[2][4] = {};
#pragma unroll
  for (int ks = 0; ks < 2; ks++) {
    s8v a2[2], b2[4];
#pragma unroll
    for (int mi = 0; mi < 2; mi++) a2[mi] = *(const s8v*)&kt[(wj2 + mi*16 + fr)*72 + ks*32 + fq*8];
#pragma unroll
    for (int ni = 0; ni < 4; ni++) b2[ni] = *(const s8v*)&rqt[(wn2 + ni*16 + fr)*72 + ks*32 + fq*8];
#pragma unroll
    for (int mi = 0; mi < 2; mi++)
#pragma unroll
      for (int ni = 0; ni < 4; ni++)
        pr[mi][ni] = __builtin_amdgcn_mfma_f32_16x16x32_bf16(a2[mi], b2[ni], pr[mi][ni], 0, 0, 0);
  }
  __syncthreads();

#pragma unroll
  for (int mi = 0; mi < 2; mi++)
#pragma unroll
    for (int ni = 0; ni < 4; ni++)
#pragma unroll
      for (int r = 0; r < 4; r++)
        P[(wj2 + mi*16 + fq*4 + r)*132 + wn2 + ni*16 + fr] = pr[mi][ni][r];
  __syncthreads();

  const float* Tt = T + h*2047 + nbase;
  float* Lb = L + ((size_t)z*1024 + i0)*768 + j0;
#pragma unroll
  for (int mi = 0; mi < 2; mi++)
#pragma unroll
    for (int ni = 0; ni < 2; ni++)
#pragma unroll
      for (int r = 0; r < 4; r++) {
        const int il = wi + mi*16 + fq*4 + r;
        const int jl = wj + ni*16 + fr;
        const int nl = 63 + il - jl;
        Lb[(size_t)il*768 + jl] = c2[mi][ni][r] + 0.125f*P[jl*132 + nl] + Tt[nl];
      }
}

// ============ softmax over 768 cols, f32 in -> bf16 out ============
__global__ __launch_bounds__(256) void softmax_k(const float* __restrict__ L, short* __restrict__ P)
{
  const long long row = blockIdx.x;
  const float* r = L + row*768;
  const int tid = threadIdx.x;
  float v0 = r[tid], v1 = r[tid+256], v2 = r[tid+512];
  float mx = fmaxf(v0, fmaxf(v1, v2));
  for (int m = 1; m < 64; m <<= 1) mx = fmaxf(mx, __shfl_xor(mx, m));
  __shared__ float redm[4], reds[4];
  if ((tid & 63) == 0) redm[tid>>6] = mx;
  __syncthreads();
  mx = fmaxf(fmaxf(redm[0], redm[1]), fmaxf(redm[2], redm[3]));
  v0 = __expf(v0 - mx); v1 = __expf(v1 - mx); v2 = __expf(v2 - mx);
  float s = v0 + v1 + v2;
  for (int m = 1; m < 64; m <<= 1) s += __shfl_xor(s, m);
  if ((tid & 63) == 0) reds[tid>>6] = s;
  __syncthreads();
  s = reds[0] + reds[1] + reds[2] + reds[3];
  const float inv = 1.f / s;
  short* o = P + row*768;
  o[tid] = f2bf(v0*inv); o[tid+256] = f2bf(v1*inv); o[tid+512] = f2bf(v2*inv);
}

// ======================= host =======================
static void gemm(hipStream_t st, const short* A, const short* B, float* Cf, short* Cb,
                 const float* bias, const float* resid,
                 int M, int N, int K, int lda, int ldb, int ldc,
                 int batches = 1,
                 long long sAo = 0, long long sAi = 0, long long sBo = 0, long long sBi = 0,
                 long long sCo = 0, long long sCi = 0, float alpha = 1.f, int relu = 0)
{
  dim3 g((N + 127)/128, (M + 127)/128, batches);
  gemm_bt<<<g, dim3(256), 0, st>>>(A, B, Cf, Cb, bias, resid, M, N, K, lda, ldb, ldc,
                                   sAo, sAi, sBo, sBi, sCo, sCi, alpha, relu);
}

static void g256_3(hipStream_t st,
    const short* A0, const short* B0, float* C0f, short* C0b, const float* bias0, const float* res0,
    int M0, int N0, float al0,
    const short* A1, const short* B1, float* C1f, short* C1b, const float* bias1, const float* res1,
    int M1, int N1, float al1,
    const short* A2, const short* B2, float* C2f, short* C2b, const float* bias2, const float* res2,
    int M2, int N2, float al2,
    int K, int relu, const TailWT* tw = nullptr, int ntail = 0)
{
  const int nbm0 = M0 >> 8, nb0 = nbm0*(N0 >> 8);
  const int nbm1 = M1 >> 8, nb1 = nbm1*(N1 >> 8);
  const int nbm2 = M2 >> 8, nb2 = M2 ? nbm2*(N2 >> 8) : 0;
  const int nb012 = nb0 + nb1 + nb2;
  TailWT tz{};
  if (tw) tz = *tw;
  gemm256<<<dim3(nb012 + ntail), dim3(512), 0, st>>>(
      A0, B0, C0f, C0b, bias0, res0, nb0, nbm0, N0, al0,
      A1, B1, C1f, C1b, bias1, res1, nb0 + nb1, nbm1, N1, al1,
      A2, B2, C2f, C2b, bias2, res2, nbm2, N2, al2,
      nb012, tz, K, relu);
}

static void g256(hipStream_t st,
    const short* A0, const short* B0, float* C0f, short* C0b, const float* bias0, const float* res0,
    int M0, int N0, float al0,
    const short* A1, const short* B1, float* C1f, short* C1b, const float* bias1, const float* res1,
    int M1, int N1, float al1,
    int K, int relu, const TailWT* tw = nullptr, int ntail = 0)
{
  g256_3(st, A0, B0, C0f, C0b, bias0, res0, M0, N0, al0,
         A1, B1, C1f, C1b, bias1, res1, M1, N1, al1,
         nullptr, nullptr, nullptr, nullptr, nullptr, nullptr, 0, 256, 1.f, K, relu, tw, ntail);
}

extern "C" void kernel_launch(void* const* d_in, const int* in_sizes, int n_in,
                              void* d_out, int out_size, void* d_ws, size_t ws_size,
                              hipStream_t stream)
{
  (void)in_sizes; (void)n_in; (void)out_size; (void)ws_size;
  const float* x     = (const float*)d_in[0];
  const float* y0    = (const float*)d_in[1];
  const float* lnxg  = (const float*)d_in[3];
  const float* lnxb  = (const float*)d_in[4];
  const float* lnyg  = (const float*)d_in[5];
  const float* lnyb  = (const float*)d_in[6];
  const float* rpb   = (const float*)d_in[12];
  const float* bo1   = (const float*)d_in[14];
  const float* bo2   = (const float*)d_in[16];
  const float* fxg   = (const float*)d_in[17];
  const float* fxbb  = (const float*)d_in[18];
  const float* fxb1  = (const float*)d_in[20];
  const float* fxb2  = (const float*)d_in[22];
  const float* fyg   = (const float*)d_in[23];
  const float* fybb  = (const float*)d_in[24];
  const float* fyb1  = (const float*)d_in[26];
  const float* fyb2  = (const float*)d_in[28];

  char* base = (char*)d_ws;
  size_t off = 0;
  auto bump = [&](size_t b) -> char* { char* p = base + off; off += (b + 255) & ~(size_t)255; return p; };

  // ---- pooled weight buffers (bf16, transposed [N,K]) ----
  short* W_A  = (short*)bump(4718592);   // resT -> wo1T (tail B)  (1536x1536)
  short* W_B  = (short*)bump(1572864);   // wqT  (tail A)          (512x1536)
  short* W_B2 = (short*)bump(1572864);   // wkT  (tail A)          (512x1536)
  short* W_C  = (short*)bump(4718592);   // wv1T -> wo2T (tail B)  (1536x1536)
  short* W_D  = (short*)bump(196608);    // relT                   (512x192)
  short* W_E  = (short*)bump(9437184);   // fx1T (tail A)          (3072x1536)
  short* W_F  = (short*)bump(9437184);   // fx2T (tail A)          (1536x3072)

  char*  uB = bump(12582912);  short* x1 = (short*)uB;   short* out1 = (short*)uB;
  char*  uC = bump(9437184);   short* y1 = (short*)uC;   short* out2 = (short*)uC;
  char*  uD = bump(9437184);
  short* y0b = (short*)uD;                       // conv -> res pair
  short* qb  = (short*)uD;                       // q -> scores
  short* kbB = (short*)(uD + 4194304);           // k -> scores
  float* Tbl   = (float*)bump(262016);           // rel bias table [8][2047]
  short* posb  = (short*)bump(786048);
  short* relqb = (short*)bump(2096128);
  char*  uG = bump(12582912);  short* v1b = (short*)uG;  short* x4ln = (short*)uG;
  char*  uH = bump(9437184);   short* v2b = (short*)uH;  short* y4ln = (short*)uH;
  char*  uI = bump(100663296);                   // big union, 100.7MB
  short* wv2T   = (short*)uI;                            // tail A, dead before logits
  float* logits = (float*)uI;                            // scores -> softmax
  short* attnT  = (short*)uI;                            // 16-20
  short* v1T    = (short*)(uI + 50331648);               // 17-20
  short* v2T    = (short*)(uI + 62914560);               // 18-19
  short* hx     = (short*)uI;                            // 25-27
  short* hy     = (short*)(uI + 25165824);               // 26-28
  short* fy1T   = (short*)(uI + 46137344);               // tail C (wo launch), used 26
  short* fy2T   = (short*)(uI + 55574528);               // tail C (wo launch), used 28
  char*  U2 = bump(50331648);
  short* attnb = (short*)U2;                     // 15-20
  float* y4    = (float*)U2;                     // 22-28

  float* outx = (float*)d_out;                   // hosts x4 (21-27)
  float* outy = (float*)d_out + 6291456;         // hosts y_f (5-22)
  float* x4  = outx;
  float* y_f = outy;

  auto WT = [&](int idx, short* dst, int R, int C) {
    wtrans<<<dim3(C/32, R/32), dim3(32,8), 0, stream>>>((const float*)d_in[idx], dst, R, C);
  };
  auto setop = [&](TailWT& tw, int i, int idx, short* dst, int R, int C) {
    tw.src[i] = (const float*)d_in[idx]; tw.dst[i] = dst;
    tw.R[i] = R; tw.C[i] = C; tw.tiles[i] = (R >> 5)*(C >> 5);
  };

  // 1. pre-launch weight transposes (only those launch1 itself consumes)
  WT(2,  W_A, 1536, 1536);    // res_w
  WT(9,  W_C, 1536, 1536);    // wv1
  WT(11, W_D, 192,  512);     // wrel
  // 2. y0 -> bf16 ; positional features ; ln_x
  conv_bf<<<4608, 256, 0, stream>>>(y0, y0b, 4718592LL);
  posemb<<<2047, 64, 0, stream>>>(posb);
  ln_k<<<4096, 256, 0, stream>>>(x, lnxg, lnxb, x1);
  // 3. relq = pos @ wrel ; rel bias table
  gemm(stream, posb, W_D, nullptr, relqb, nullptr, nullptr, 2047, 512, 192, 192, 192, 512);
  relbias_k<<<2047, 256, 0, stream>>>(rpb, relqb, Tbl);
  // 4. launch1: res = y0@res_w + v1 = x1@wv1  [168 gemm + 88 tail = 256 blocks]
  //    tail A: wq, wk, wv2, fx1, fx2
  TailWT tA{};
  setop(tA, 0, 7,  W_B,  1536, 512);
  setop(tA, 1, 8,  W_B2, 1536, 512);
  setop(tA, 2, 10, wv2T, 1536, 1536);
  setop(tA, 3, 19, W_E,  1536, 3072);
  setop(tA, 4, 21, W_F,  3072, 1536);
  g256(stream, y0b, W_A, y_f, nullptr, nullptr, nullptr, 3072, 1536, 1.f,
       x1, W_C, nullptr, v1b, nullptr, nullptr, 4096, 1536, 1.f, 1536, 0, &tA, 88);
  // 5. ln_y
  ln_k<<<3072, 256, 0, stream>>>(y_f, lnyg, lnyb, y1);
  // 6. v2 + q + k  [128 gemm + 88 tail = 216 blocks]; tail B: wo1->W_A, wo2->W_C
  TailWT tB{};
  setop(tB, 0, 13, W_A, 1536, 1536);
  setop(tB, 1, 15, W_C, 1536, 1536);
  g256_3(stream, y1, wv2T, nullptr, v2b, nullptr, nullptr, 3072, 1536, 1.f,
         x1, W_B, nullptr, qb, nullptr, nullptr, 4096, 512, 0.125f,
         y1, W_B2, nullptr, kbB, nullptr, nullptr, 3072, 512, 1.f, 1536, 0, &tB, 88);
  // 7. fused scores ; softmax
  scores_k<<<dim3(12,16,32), 256, 0, stream>>>(qb, kbB, relqb, Tbl, logits);
  softmax_k<<<32768, 256, 0, stream>>>(logits, attnb);
  // 8. transposes for attention GEMMs
  btrans<<<dim3(24,32,32), dim3(32,8), 0, stream>>>(attnb, attnT, 768, 1024,
       8LL*786432, 786432, 8LL*786432, 786432);
  btrans<<<dim3(6,32,32), dim3(32,8), 0, stream>>>(v1b, v1T, 1536, 1024,
       1024LL*1536, 192, 8LL*196608, 196608);
  btrans<<<dim3(6,24,32), dim3(32,8), 0, stream>>>(v2b, v2T, 1536, 768,
       768LL*1536, 192, 8LL*147456, 147456);
  // 9. out1 = attn @ v2 ; out2 = attn^T @ v1
  gemm(stream, attnb, v2T, nullptr, out1, nullptr, nullptr, 1024, 192, 768, 768, 768, 1536,
       32, 8LL*786432, 786432, 8LL*147456, 147456, 1024LL*1536, 192);
  gemm(stream, attnT, v1T, nullptr, out2, nullptr, nullptr, 768, 192, 1024, 1024, 1024, 1536,
       32, 8LL*786432, 786432, 8LL*196608, 196608, 768LL*1536, 192);
  // 10. wo-pair: x4 = x + out1@wo1 + bo1 ; y4 = y + out2@wo2 + bo2
  //     tail C: fy1 -> fy1T, fy2 -> fy2T (attnT/v1T/v2T regions dead)
  TailWT tC{};
  setop(tC, 0, 25, fy1T, 1536, 3072);
  setop(tC, 1, 27, fy2T, 3072, 1536);
  g256(stream, out1, W_A, x4, nullptr, bo1, x, 4096, 1536, 1.f,
       out2, W_C, y4, nullptr, bo2, y_f, 3072, 1536, 1.f, 1536, 0, &tC, 88);
  // 11. FFN LayerNorms
  ln_k<<<4096, 256, 0, stream>>>(x4, fxg, fxbb, x4ln);
  ln_k<<<3072, 256, 0, stream>>>(y4, fyg, fybb, y4ln);
  // 12. paired: hidden = relu(ln @ w1 + b1)
  g256(stream, x4ln, W_E, nullptr, hx, fxb1, nullptr, 4096, 3072, 1.f,
       y4ln, fy1T, nullptr, hy, fyb1, nullptr, 3072, 3072, 1.f, 1536, 1);
  // 13. paired: out = resid + h @ w2 + b2  (in-place on outx)
  g256(stream, hx, W_F, outx, nullptr, fxb2, x4, 4096, 1536, 1.f,
       hy, fy2T, outy, nullptr, fyb2, y4, 3072, 1536, 1.f, 3072, 0);
}

// Round 9
// 697.493 us; speedup vs baseline: 1.1102x; 1.1102x over previous
//
#include <hip/hip_runtime.h>
#include <stdint.h>
#include <math.h>

typedef __attribute__((ext_vector_type(8))) short s8v;
typedef __attribute__((ext_vector_type(4))) short s4v;
typedef __attribute__((ext_vector_type(4))) float f4v;

#define DEV static __device__ __forceinline__

DEV short f2bf(float f) {
  uint32_t u = __builtin_bit_cast(uint32_t, f);
  u += 0x7FFFu + ((u >> 16) & 1u);   // round-to-nearest-even
  return (short)(u >> 16);
}
DEV float bf2f(short s) {
  uint32_t u = ((uint32_t)(uint16_t)s) << 16;
  return __builtin_bit_cast(float, u);
}

#define GLD16(g, l) __builtin_amdgcn_global_load_lds( \
    (const __attribute__((address_space(1))) void*)(g), \
    (__attribute__((address_space(3))) void*)(l), 16, 0, 0)

// ================= 128x128 GEMM (m97 structure) for small/odd/batched shapes =========
__global__ __launch_bounds__(256) void gemm_bt(
    const short* __restrict__ A, const short* __restrict__ B,
    float* Cf, short* Cb,
    const float* __restrict__ bias, const float* resid,
    int M, int N, int K, int lda, int ldb, int ldc,
    long long sAo, long long sAi, long long sBo, long long sBi,
    long long sCo, long long sCi, float alpha, int relu)
{
  __shared__ __align__(16) short lA[128*32];
  __shared__ __align__(16) short lB[128*32];
  const int z = blockIdx.z, zo = z >> 3, zi = z & 7;
  const short* Ab = A + zo*sAo + zi*sAi;
  const short* Bb = B + zo*sBo + zi*sBi;
  const long long cOff = zo*sCo + zi*sCi;

  const int m0 = blockIdx.y*128, n0 = blockIdx.x*128;
  const int tid = threadIdx.x, lane = tid & 63, wv = tid >> 6;
  const int wm = (wv >> 1)*64, wn = (wv & 1)*64;
  const int fr = lane & 15, fq = lane >> 4;

  f4v acc[4][4] = {};

  const int rA0 = min(m0 + (tid >> 2), M - 1);
  const int rA1 = min(m0 + 64 + (tid >> 2), M - 1);
  const int rB0 = min(n0 + (tid >> 2), N - 1);
  const int rB1 = min(n0 + 64 + (tid >> 2), N - 1);
  const int pc = (tid & 3) * 8;
  const short* gA0 = Ab + (size_t)rA0*lda + pc;
  const short* gA1 = Ab + (size_t)rA1*lda + pc;
  const short* gB0 = Bb + (size_t)rB0*ldb + pc;
  const short* gB1 = Bb + (size_t)rB1*ldb + pc;
  short* dA0 = lA + (wv*64)*8;
  short* dA1 = lA + (256 + wv*64)*8;
  short* dB0 = lB + (wv*64)*8;
  short* dB1 = lB + (256 + wv*64)*8;

  for (int k0 = 0; k0 < K; k0 += 32) {
    GLD16(gA0 + k0, dA0);
    GLD16(gA1 + k0, dA1);
    GLD16(gB0 + k0, dB0);
    GLD16(gB1 + k0, dB1);
    __syncthreads();
    s8v af[4], bg[4];
#pragma unroll
    for (int i = 0; i < 4; i++) {
      af[i] = *(const s8v*)&lA[(wm + i*16 + fr)*32 + fq*8];
      bg[i] = *(const s8v*)&lB[(wn + i*16 + fr)*32 + fq*8];
    }
#pragma unroll
    for (int mi = 0; mi < 4; mi++)
#pragma unroll
      for (int ni = 0; ni < 4; ni++)
        acc[mi][ni] = __builtin_amdgcn_mfma_f32_16x16x32_bf16(af[mi], bg[ni], acc[mi][ni], 0, 0, 0);
    __syncthreads();
  }

#pragma unroll
  for (int mi = 0; mi < 4; mi++) {
    const int row = m0 + wm + mi*16 + fq*4;
#pragma unroll
    for (int ni = 0; ni < 4; ni++) {
      const int col = n0 + wn + ni*16 + fr;
      if (col >= N) continue;
      const float bv = bias ? bias[col] : 0.f;
#pragma unroll
      for (int r = 0; r < 4; r++) {
        if (row + r >= M) continue;
        float v = acc[mi][ni][r] * alpha + bv;
        const long long idx = cOff + (long long)(row + r)*ldc + col;
        if (resid) v += resid[idx];
        if (relu) v = fmaxf(v, 0.f);
        if (Cf) Cf[idx] = v;
        if (Cb) Cb[idx] = f2bf(v);
      }
    }
  }
}

// ================= 256x256 8-phase GEMM (r6 single-barrier schedule) ======
// waits only at ph4/ph8 (vmcnt(6)); stage ring 1 phase after last read.
#define ST_A(buf, ks, tt) do { const int ko = ((tt)<<6) + ((ks)<<5); \
    GLD16(gA0 + ko, ldA + ((buf)*2+(ks))*8192); \
    GLD16(gA1 + ko, ldA + ((buf)*2+(ks))*8192 + 4096); } while(0)
#define ST_B(buf, ks, tt) do { const int ko = ((tt)<<6) + ((ks)<<5); \
    GLD16(gB0 + ko, ldB + ((buf)*2+(ks))*8192); \
    GLD16(gB1 + ko, ldB + ((buf)*2+(ks))*8192 + 4096); } while(0)

#define PH256(buf, ks, mig, READB, DOWAIT, ...) do { \
    s8v av[4]; \
    const int rb = ((buf)*2+(ks))*8192; \
    _Pragma("unroll") for (int q2 = 0; q2 < 4; q2++) av[q2] = *(const s8v*)&smem[rb + aoff[(mig)*4+q2]]; \
    if (READB) { _Pragma("unroll") for (int q2 = 0; q2 < 4; q2++) bv[q2] = *(const s8v*)&smem[32768 + rb + boff[q2]]; } \
    __VA_ARGS__; \
    if (DOWAIT == 1) asm volatile("s_waitcnt vmcnt(6)" ::: "memory"); \
    if (DOWAIT == 2) asm volatile("s_waitcnt vmcnt(0)" ::: "memory"); \
    __builtin_amdgcn_s_barrier(); \
    asm volatile("s_waitcnt lgkmcnt(0)" ::: "memory"); \
    __builtin_amdgcn_s_setprio(1); \
    _Pragma("unroll") for (int q2 = 0; q2 < 4; q2++) \
      _Pragma("unroll") for (int u2 = 0; u2 < 4; u2++) \
        acc[(mig)*4+q2][u2] = __builtin_amdgcn_mfma_f32_16x16x32_bf16(av[q2], bv[u2], acc[(mig)*4+q2][u2], 0, 0, 0); \
    __builtin_amdgcn_s_setprio(0); \
  } while(0)

__global__ __launch_bounds__(512, 2) void gemm256(
    const short* __restrict__ A0p, const short* __restrict__ B0p,
    float* C0f, short* C0b, const float* __restrict__ bias0, const float* res0,
    int nb0, int nbm0, int N0, float al0,
    const short* __restrict__ A1p, const short* __restrict__ B1p,
    float* C1f, short* C1b, const float* __restrict__ bias1, const float* res1,
    int nb01, int nbm1, int N1, float al1,
    const short* __restrict__ A2p, const short* __restrict__ B2p,
    float* C2f, short* C2b, const float* __restrict__ bias2, const float* res2,
    int nbm2, int N2, float al2,
    int K, int relu)
{
  __shared__ __align__(16) short smem[65536];   // 128 KiB
  const int total = gridDim.x;
  int bid = blockIdx.x;
  if ((total & 7) == 0) bid = (bid & 7)*(total >> 3) + (bid >> 3);   // bijective XCD swizzle
  const short* A; const short* B; float* Cf; short* Cb; const float* bias; const float* resid;
  int tile, nbm, N; float alpha;
  if (bid < nb0)       { A = A0p; B = B0p; Cf = C0f; Cb = C0b; bias = bias0; resid = res0;
                         tile = bid; nbm = nbm0; N = N0; alpha = al0; }
  else if (bid < nb01) { A = A1p; B = B1p; Cf = C1f; Cb = C1b; bias = bias1; resid = res1;
                         tile = bid - nb0; nbm = nbm1; N = N1; alpha = al1; }
  else                 { A = A2p; B = B2p; Cf = C2f; Cb = C2b; bias = bias2; resid = res2;
                         tile = bid - nb01; nbm = nbm2; N = N2; alpha = al2; }
  const int bm = tile % nbm, bn = tile / nbm;   // col-major: consecutive tiles share B panel
  const int m0 = bm << 8, n0 = bn << 8;
  const int t = threadIdx.x, lane = t & 63, w = t >> 6;
  const int wm = w >> 2, wn = w & 3;
  const int fr = lane & 15, fq = lane >> 4;
  const int ntk = K >> 6;                        // requires K % 128 == 0, K >= 256

  // staging: region = 256 rows x 32 cols; pre-swizzled global source
  const int r0 = t >> 2, r1 = 128 + (t >> 2), gsw = t & 3;
  const int cs0 = (gsw ^ ((r0 >> 1) & 3)) << 3;
  const int cs1 = (gsw ^ ((r1 >> 1) & 3)) << 3;
  const short* gA0 = A + (size_t)(m0 + r0)*K + cs0;
  const short* gA1 = A + (size_t)(m0 + r1)*K + cs1;
  const short* gB0 = B + (size_t)(n0 + r0)*K + cs0;
  const short* gB1 = B + (size_t)(n0 + r1)*K + cs1;
  short* const ldA = smem + w*512;
  short* const ldB = smem + 32768 + w*512;

  // ds_read fragment offsets (swizzled)
  int aoff[8], boff[4];
#pragma unroll
  for (int mi = 0; mi < 8; mi++) { const int r = wm*128 + mi*16 + fr; aoff[mi] = r*32 + ((fq ^ ((r >> 1) & 3)) << 3); }
#pragma unroll
  for (int ni = 0; ni < 4; ni++) { const int r = wn*64 + ni*16 + fr; boff[ni] = r*32 + ((fq ^ ((r >> 1) & 3)) << 3); }

  f4v acc[8][4] = {};
  s8v bv[4];

  // prologue: buf0 (t0) fully + buf1 (t1) B10,A10,B11 -> 7 stages, 14 loads.
  ST_A(0,0,0); ST_B(0,0,0); ST_A(0,1,0); ST_B(0,1,0);
  ST_B(1,0,1); ST_A(1,0,1); ST_B(1,1,1);
  asm volatile("s_waitcnt vmcnt(6)" ::: "memory");
  __builtin_amdgcn_s_barrier();
  asm volatile("" ::: "memory");

  for (int it = 0, nit = (ntk >> 1) - 1; it < nit; ++it) {
    const int t1 = 2*it + 1, t2 = 2*it + 2, t3 = 2*it + 3;
    PH256(0,0,0, 1,0, ST_A(1,1,t1));   // ph1
    PH256(0,0,1, 0,0, ST_B(0,0,t2));   // ph2
    PH256(0,1,0, 1,0, ST_A(0,0,t2));   // ph3
    PH256(0,1,1, 0,1, ST_B(0,1,t2));   // ph4 + vmcnt(6)
    PH256(1,0,0, 1,0, ST_A(0,1,t2));   // ph5
    PH256(1,0,1, 0,0, ST_B(1,0,t3));   // ph6
    PH256(1,1,0, 1,0, ST_A(1,0,t3));   // ph7
    PH256(1,1,1, 0,1, ST_B(1,1,t3));   // ph8 + vmcnt(6)
  }
  // peeled final iteration: only A11 left to stage; drain at ph4
  PH256(0,0,0, 1,0, ST_A(1,1,ntk-1));
  PH256(0,0,1, 0,0, );
  PH256(0,1,0, 1,0, );
  PH256(0,1,1, 0,2, );                 // vmcnt(0): buf1 fully resident
  PH256(1,0,0, 1,0, );
  PH256(1,0,1, 0,0, );
  PH256(1,1,0, 1,0, );
  PH256(1,1,1, 0,0, );

  // epilogue
#pragma unroll
  for (int mi = 0; mi < 8; mi++) {
    const int row = m0 + wm*128 + mi*16 + fq*4;
#pragma unroll
    for (int ni = 0; ni < 4; ni++) {
      const int col = n0 + wn*64 + ni*16 + fr;
      const float bvv = bias ? bias[col] : 0.f;
#pragma unroll
      for (int r = 0; r < 4; r++) {
        float v = acc[mi][ni][r]*alpha + bvv;
        const size_t idx = (size_t)(row + r)*N + col;
        if (resid) v += resid[idx];
        if (relu) v = fmaxf(v, 0.f);
        if (Cf) Cf[idx] = v;
        else Cb[idx] = f2bf(v);
      }
    }
  }
}

// ============ batched weight transpose: up to 8 f32[R,C] -> bf16[C,R], 1 tile/block ======
struct WTB {
  const float* src[8]; short* dst[8];
  int R[8], C[8], start[8];   // start[o] = first tile id of op o; unused -> INT_MAX
  int NT;
};

__global__ __launch_bounds__(256) void wtransN(WTB b)
{
  __shared__ float t[32][33];
  const int id = blockIdx.x;
  if (id >= b.NT) return;
  int op = 0;
#pragma unroll
  for (int o = 1; o < 8; o++) if (id >= b.start[o]) op = o;
  const int loc = id - b.start[op];
  const int Cd = b.C[op], Rd = b.R[op];
  const int ncx = Cd >> 5;
  const int cx = (loc % ncx) << 5, ry = (loc / ncx) << 5;
  const float* s = b.src[op];
  short* d = b.dst[op];
  const int tx = threadIdx.x, ty = threadIdx.y;
#pragma unroll
  for (int k = 0; k < 4; k++)
    t[ty + k*8][tx] = s[(size_t)(ry + ty + k*8)*Cd + cx + tx];
  __syncthreads();
#pragma unroll
  for (int k = 0; k < 4; k++)
    d[(size_t)(cx + ty + k*8)*Rd + ry + tx] = f2bf(t[tx][ty + k*8]);
}

// ============ batched bf16 transpose ============
__global__ __launch_bounds__(256) void btrans(const short* __restrict__ src, short* __restrict__ dst,
    int ls, int ld_, long long sSo, long long sSi, long long sDo, long long sDi)
{
  __shared__ short t[32][33];
  const int z = blockIdx.z;
  const short* S = src + (z>>3)*sSo + (z&7)*sSi;
  short* D = dst + (z>>3)*sDo + (z&7)*sDi;
  const int c0 = blockIdx.x*32, r0 = blockIdx.y*32;
  const int tx = threadIdx.x, ty = threadIdx.y;
#pragma unroll
  for (int k = 0; k < 4; k++)
    t[ty + k*8][tx] = S[(size_t)(r0 + ty + k*8)*ls + c0 + tx];
  __syncthreads();
#pragma unroll
  for (int k = 0; k < 4; k++)
    D[(size_t)(c0 + ty + k*8)*ld_ + r0 + tx] = t[tx][ty + k*8];
}

// ============ f32 -> bf16 convert ============
__global__ __launch_bounds__(256) void conv_bf(const float* __restrict__ src,
                                               short* __restrict__ dst, long long n)
{
  const long long i = ((long long)blockIdx.x*256 + threadIdx.x)*4;
  if (i >= n) return;
  const float4 v = *(const float4*)(src + i);
  s4v o = { f2bf(v.x), f2bf(v.y), f2bf(v.z), f2bf(v.w) };
  *(s4v*)(dst + i) = o;
}

// ============ LayerNorm over 1536 cols, f32 in -> bf16 out ============
__global__ __launch_bounds__(256) void ln_k(const float* __restrict__ in,
    const float* __restrict__ gam, const float* __restrict__ bet, short* __restrict__ out)
{
  const long long row = blockIdx.x;
  const float* r = in + row*1536;
  const int tid = threadIdx.x;
  float v[6], s = 0.f, s2 = 0.f;
#pragma unroll
  for (int i = 0; i < 6; i++) { v[i] = r[tid + i*256]; s += v[i]; s2 += v[i]*v[i]; }
  for (int m = 1; m < 64; m <<= 1) { s += __shfl_xor(s, m); s2 += __shfl_xor(s2, m); }
  __shared__ float rs[4], rs2[4];
  if ((tid & 63) == 0) { rs[tid>>6] = s; rs2[tid>>6] = s2; }
  __syncthreads();
  s = rs[0]+rs[1]+rs[2]+rs[3]; s2 = rs2[0]+rs2[1]+rs2[2]+rs2[3];
  const float mu  = s * (1.f/1536.f);
  const float var = s2 * (1.f/1536.f) - mu*mu;
  const float inv = rsqrtf(var + 1e-5f);
  short* o = out + row*1536;
#pragma unroll
  for (int i = 0; i < 6; i++) { int c = tid + i*256; o[c] = f2bf((v[i]-mu)*inv*gam[c] + bet[c]); }
}

// ============ positional features: out bf16 [2047][192] ============
__global__ __launch_bounds__(64) void posemb(short* __restrict__ out)
{
  const int i = blockIdx.x;
  const int j = threadIdx.x;
  const float dist = (float)(i - 1023);
  const float absd = fabsf(dist);
  float fe = 0.f, fc = 0.f, prob = 0.f;
  if (j < 32) {
    const float hl = exp2f(3.f + 7.f*(float)j/31.f);
    fe = expf(-0.6931471805599453f/hl * absd);
    const float width = exp2f((float)(j+1)) - 1.f;
    fc = (width > absd) ? 1.f : 0.f;
    const float m = 32.f*(float)(j+1);
    const float conc = (m/16.f)*(m/16.f);
    const float rate = m/256.f;
    const float logp = (absd > 0.f ? (conc-1.f)*logf(absd) : -INFINITY) - rate*absd;
    const float logn = lgammaf(conc) - conc*logf(rate);
    prob = expf(logp - logn) + 1e-8f;
  }
  float mx = prob;
  for (int m = 1; m < 32; m <<= 1) mx = fmaxf(mx, __shfl_xor(mx, m));
  if (j < 32) {
    const float fg = prob / mx;
    const float sg = dist > 0.f ? 1.f : (dist < 0.f ? -1.f : 0.f);
    const size_t base = (size_t)i*192;
    out[base + j]       = f2bf(fe);
    out[base + 32 + j]  = f2bf(fc);
    out[base + 64 + j]  = f2bf(fg);
    out[base + 96 + j]  = f2bf(sg*fe);
    out[base + 128 + j] = f2bf(sg*fc);
    out[base + 160 + j] = f2bf(sg*fg);
  }
}

// ============ rel bias table: T[h][n] = dot64(rpb[h], relq[n,h*64:]) ============
__global__ __launch_bounds__(256) void relbias_k(const float* __restrict__ rpb,
    const short* __restrict__ relq, float* __restrict__ T)
{
  const int n = blockIdx.x;
  const int tid = threadIdx.x;
  const int h = tid >> 5, l = tid & 31;
  const int d = l*2;
  float s = rpb[h*64+d]   * bf2f(relq[(size_t)n*512 + h*64 + d])
          + rpb[h*64+d+1] * bf2f(relq[(size_t)n*512 + h*64 + d+1]);
  for (int m = 1; m < 32; m <<= 1) s += __shfl_xor(s, m);
  if (l == 0) T[h*2047 + n] = s;
}

// ============ fused scores: L[z,i,j] = q·k^T + 0.125*(k@relq^T)[j,63+il-jl] + T[h,n] =====
__global__ __launch_bounds__(256) void scores_k(
    const short* __restrict__ qb, const short* __restrict__ kb,
    const short* __restrict__ relq, const float* __restrict__ T,
    float* __restrict__ L)
{
  __shared__ __align__(16) short smem[21504];
  short* kt  = smem;                 // 64*72
  short* qt  = smem + 4608;          // 64*72
  short* rqt = smem + 4608;          // 128*72 (over qt)
  float* P   = (float*)(smem + 4608);// 64*132 f32 (over rqt)

  const int z = blockIdx.z, b = z >> 3, h = z & 7;
  const int j0 = blockIdx.x*64, i0 = blockIdx.y*64;
  const int tid = threadIdx.x, lane = tid & 63, wv = tid >> 6;
  const int fr = lane & 15, fq = lane >> 4;

  {
    const short* kg = kb + (size_t)(b*768  + j0)*512 + h*64;
    const short* qg = qb + (size_t)(b*1024 + i0)*512 + h*64;
    for (int c = tid; c < 512; c += 256) {
      const int r = c >> 3, ch = (c & 7)*8;
      *(s8v*)&kt[r*72 + ch] = *(const s8v*)&kg[(size_t)r*512 + ch];
      *(s8v*)&qt[r*72 + ch] = *(const s8v*)&qg[(size_t)r*512 + ch];
    }
  }
  __syncthreads();

  const int wi = (wv & 1)*32, wj = (wv >> 1)*32;
  f4v c2[2][2] = {};
#pragma unroll
  for (int ks = 0; ks < 2; ks++) {
    s8v aq[2], bk[2];
#pragma unroll
    for (int mi = 0; mi < 2; mi++) aq[mi] = *(const s8v*)&qt[(wi + mi*16 + fr)*72 + ks*32 + fq*8];
#pragma unroll
    for (int ni = 0; ni < 2; ni++) bk[ni] = *(const s8v*)&kt[(wj + ni*16 + fr)*72 + ks*32 + fq*8];
#pragma unroll
    for (int mi = 0; mi < 2; mi++)
#pragma unroll
      for (int ni = 0; ni < 2; ni++)
        c2[mi][ni] = __builtin_amdgcn_mfma_f32_16x16x32_bf16(aq[mi], bk[ni], c2[mi][ni], 0, 0, 0);
  }
  __syncthreads();

  const int nbase = 704 + i0 - j0;
  {
    const short* rg = relq + (size_t)nbase*512 + h*64;
    for (int c = tid; c < 1024; c += 256) {
      const int r = c >> 3, ch = (c & 7)*8;
      *(s8v*)&rqt[r*72 + ch] = *(const s8v*)&rg[(size_t)r*512 + ch];
    }
  }
  __syncthreads();

  const int wj2 = (wv & 1)*32, wn2 = (wv >> 1)*64;
  f4v pr[2][4] = {};
#pragma unroll
  for (int ks = 0; ks < 2; ks++) {
    s8v a2[2], b2[4];
#pragma unroll
    for (int mi = 0; mi < 2; mi++) a2[mi] = *(const s8v*)&kt[(wj2 + mi*16 + fr)*72 + ks*32 + fq*8];
#pragma unroll
    for (int ni = 0; ni < 4; ni++) b2[ni] = *(const s8v*)&rqt[(wn2 + ni*16 + fr)*72 + ks*32 + fq*8];
#pragma unroll
    for (int mi = 0; mi < 2; mi++)
#pragma unroll
      for (int ni = 0; ni < 4; ni++)
        pr[mi][ni] = __builtin_amdgcn_mfma_f32_16x16x32_bf16(a2[mi], b2[ni], pr[mi][ni], 0, 0, 0);
  }
  __syncthreads();

#pragma unroll
  for (int mi = 0; mi < 2; mi++)
#pragma unroll
    for (int ni = 0; ni < 4; ni++)
#pragma unroll
      for (int r = 0; r < 4; r++)
        P[(wj2 + mi*16 + fq*4 + r)*132 + wn2 + ni*16 + fr] = pr[mi][ni][r];
  __syncthreads();

  const float* Tt = T + h*2047 + nbase;
  float* Lb = L + ((size_t)z*1024 + i0)*768 + j0;
#pragma unroll
  for (int mi = 0; mi < 2; mi++)
#pragma unroll
    for (int ni = 0; ni < 2; ni++)
#pragma unroll
      for (int r = 0; r < 4; r++) {
        const int il = wi + mi*16 + fq*4 + r;
        const int jl = wj + ni*16 + fr;
        const int nl = 63 + il - jl;
        Lb[(size_t)il*768 + jl] = c2[mi][ni][r] + 0.125f*P[jl*132 + nl] + Tt[nl];
      }
}

// ============ softmax over 768 cols, f32 in -> bf16 out ============
__global__ __launch_bounds__(256) void softmax_k(const float* __restrict__ L, short* __restrict__ P)
{
  const long long row = blockIdx.x;
  const float* r = L + row*768;
  const int tid = threadIdx.x;
  float v0 = r[tid], v1 = r[tid+256], v2 = r[tid+512];
  float mx = fmaxf(v0, fmaxf(v1, v2));
  for (int m = 1; m < 64; m <<= 1) mx = fmaxf(mx, __shfl_xor(mx, m));
  __shared__ float redm[4], reds[4];
  if ((tid & 63) == 0) redm[tid>>6] = mx;
  __syncthreads();
  mx = fmaxf(fmaxf(redm[0], redm[1]), fmaxf(redm[2], redm[3]));
  v0 = __expf(v0 - mx); v1 = __expf(v1 - mx); v2 = __expf(v2 - mx);
  float s = v0 + v1 + v2;
  for (int m = 1; m < 64; m <<= 1) s += __shfl_xor(s, m);
  if ((tid & 63) == 0) reds[tid>>6] = s;
  __syncthreads();
  s = reds[0] + reds[1] + reds[2] + reds[3];
  const float inv = 1.f / s;
  short* o = P + row*768;
  o[tid] = f2bf(v0*inv); o[tid+256] = f2bf(v1*inv); o[tid+512] = f2bf(v2*inv);
}

// ======================= host =======================
static void gemm(hipStream_t st, const short* A, const short* B, float* Cf, short* Cb,
                 const float* bias, const float* resid,
                 int M, int N, int K, int lda, int ldb, int ldc,
                 int batches = 1,
                 long long sAo = 0, long long sAi = 0, long long sBo = 0, long long sBi = 0,
                 long long sCo = 0, long long sCi = 0, float alpha = 1.f, int relu = 0)
{
  dim3 g((N + 127)/128, (M + 127)/128, batches);
  gemm_bt<<<g, dim3(256), 0, st>>>(A, B, Cf, Cb, bias, resid, M, N, K, lda, ldb, ldc,
                                   sAo, sAi, sBo, sBi, sCo, sCi, alpha, relu);
}

static void g256_3(hipStream_t st,
    const short* A0, const short* B0, float* C0f, short* C0b, const float* bias0, const float* res0,
    int M0, int N0, float al0,
    const short* A1, const short* B1, float* C1f, short* C1b, const float* bias1, const float* res1,
    int M1, int N1, float al1,
    const short* A2, const short* B2, float* C2f, short* C2b, const float* bias2, const float* res2,
    int M2, int N2, float al2,
    int K, int relu)
{
  const int nbm0 = M0 >> 8, nb0 = nbm0*(N0 >> 8);
  const int nbm1 = M1 >> 8, nb1 = nbm1*(N1 >> 8);
  const int nbm2 = M2 >> 8, nb2 = M2 ? nbm2*(N2 >> 8) : 0;
  gemm256<<<dim3(nb0 + nb1 + nb2), dim3(512), 0, st>>>(
      A0, B0, C0f, C0b, bias0, res0, nb0, nbm0, N0, al0,
      A1, B1, C1f, C1b, bias1, res1, nb0 + nb1, nbm1, N1, al1,
      A2, B2, C2f, C2b, bias2, res2, nbm2, N2, al2, K, relu);
}

static void g256(hipStream_t st,
    const short* A0, const short* B0, float* C0f, short* C0b, const float* bias0, const float* res0,
    int M0, int N0, float al0,
    const short* A1, const short* B1, float* C1f, short* C1b, const float* bias1, const float* res1,
    int M1, int N1, float al1,
    int K, int relu)
{
  g256_3(st, A0, B0, C0f, C0b, bias0, res0, M0, N0, al0,
         A1, B1, C1f, C1b, bias1, res1, M1, N1, al1,
         nullptr, nullptr, nullptr, nullptr, nullptr, nullptr, 0, 256, 1.f, K, relu);
}

extern "C" void kernel_launch(void* const* d_in, const int* in_sizes, int n_in,
                              void* d_out, int out_size, void* d_ws, size_t ws_size,
                              hipStream_t stream)
{
  (void)in_sizes; (void)n_in; (void)out_size; (void)ws_size;
  const float* x     = (const float*)d_in[0];
  const float* y0    = (const float*)d_in[1];
  const float* lnxg  = (const float*)d_in[3];
  const float* lnxb  = (const float*)d_in[4];
  const float* lnyg  = (const float*)d_in[5];
  const float* lnyb  = (const float*)d_in[6];
  const float* rpb   = (const float*)d_in[12];
  const float* bo1   = (const float*)d_in[14];
  const float* bo2   = (const float*)d_in[16];
  const float* fxg   = (const float*)d_in[17];
  const float* fxbb  = (const float*)d_in[18];
  const float* fxb1  = (const float*)d_in[20];
  const float* fxb2  = (const float*)d_in[22];
  const float* fyg   = (const float*)d_in[23];
  const float* fybb  = (const float*)d_in[24];
  const float* fyb1  = (const float*)d_in[26];
  const float* fyb2  = (const float*)d_in[28];

  char* base = (char*)d_ws;
  size_t off = 0;
  auto bump = [&](size_t b) -> char* { char* p = base + off; off += (b + 255) & ~(size_t)255; return p; };

  // ---- pooled weight buffers (bf16, transposed [N,K]) ----
  short* W_A  = (short*)bump(4718592);   // resT -> wo1T           (1536x1536)
  short* W_B  = (short*)bump(1572864);   // wqT                    (512x1536)
  short* W_B2 = (short*)bump(1572864);   // wkT                    (512x1536)
  short* W_C  = (short*)bump(4718592);   // wv1T -> wo2T           (1536x1536)
  short* W_D  = (short*)bump(196608);    // relT                   (512x192)
  short* W_E  = (short*)bump(9437184);   // fx1T                   (3072x1536)
  short* W_F  = (short*)bump(9437184);   // fx2T                   (1536x3072)

  char*  uB = bump(12582912);  short* x1 = (short*)uB;   short* out1 = (short*)uB;
  char*  uC = bump(9437184);   short* y1 = (short*)uC;   short* out2 = (short*)uC;
  char*  uD = bump(9437184);
  short* y0b = (short*)uD;                       // conv -> res pair
  short* qb  = (short*)uD;                       // q -> scores
  short* kbB = (short*)(uD + 4194304);           // k -> scores
  float* Tbl   = (float*)bump(262016);           // rel bias table [8][2047]
  short* posb  = (short*)bump(786048);
  short* relqb = (short*)bump(2096128);
  char*  uG = bump(12582912);  short* v1b = (short*)uG;  short* x4ln = (short*)uG;
  char*  uH = bump(9437184);   short* v2b = (short*)uH;  short* y4ln = (short*)uH;
  char*  uI = bump(100663296);                   // big union, 100.7MB
  short* wv2T   = (short*)uI;                            // B1, dead before logits
  float* logits = (float*)uI;                            // scores -> softmax
  short* attnT  = (short*)uI;                            // 16-20
  short* v1T    = (short*)(uI + 50331648);               // 17-20
  short* v2T    = (short*)(uI + 62914560);               // 18-19
  short* hx     = (short*)uI;                            // 25-27
  short* hy     = (short*)(uI + 25165824);               // 26-28
  short* fy1T   = (short*)(uI + 46137344);               // B3, used ffn1
  short* fy2T   = (short*)(uI + 55574528);               // B3, used ffn2
  char*  U2 = bump(50331648);
  short* attnb = (short*)U2;                     // 15-20
  float* y4    = (float*)U2;                     // 22-28

  float* outx = (float*)d_out;                   // hosts x4 (21-27)
  float* outy = (float*)d_out + 6291456;         // hosts y_f (5-22)
  float* x4  = outx;
  float* y_f = outy;

  auto addop = [&](WTB& b, int i, int idx, short* dst, int R, int C) {
    b.src[i] = (const float*)d_in[idx]; b.dst[i] = dst;
    b.R[i] = R; b.C[i] = C; b.start[i] = b.NT; b.NT += (R >> 5)*(C >> 5);
  };
  auto finwtb = [&](WTB& b, int n) {
    for (int i = n; i < 8; i++) { b.start[i] = 0x7fffffff; b.src[i] = nullptr; b.dst[i] = nullptr; b.R[i] = 32; b.C[i] = 32; }
  };

  // B1: all weights needed through v2qk + ffn-x  [17760 tiles]
  WTB b1{}; b1.NT = 0;
  addop(b1, 0, 2,  W_A,  1536, 1536);   // res_w
  addop(b1, 1, 11, W_D,  192,  512);    // wrel
  addop(b1, 2, 9,  W_C,  1536, 1536);   // wv1
  addop(b1, 3, 10, wv2T, 1536, 1536);   // wv2
  addop(b1, 4, 7,  W_B,  1536, 512);    // wq
  addop(b1, 5, 8,  W_B2, 1536, 512);    // wk
  addop(b1, 6, 19, W_E,  1536, 3072);   // fx_w1
  addop(b1, 7, 21, W_F,  3072, 1536);   // fx_w2
  wtransN<<<dim3(b1.NT), dim3(32,8), 0, stream>>>(b1);

  // prep: y0 -> bf16 ; positional features ; ln_x
  conv_bf<<<4608, 256, 0, stream>>>(y0, y0b, 4718592LL);
  posemb<<<2047, 64, 0, stream>>>(posb);
  ln_k<<<4096, 256, 0, stream>>>(x, lnxg, lnxb, x1);
  // relq = pos @ wrel ; rel bias table
  gemm(stream, posb, W_D, nullptr, relqb, nullptr, nullptr, 2047, 512, 192, 192, 192, 512);
  relbias_k<<<2047, 256, 0, stream>>>(rpb, relqb, Tbl);
  // launch1: res = y0@res_w -> y_f + v1 = x1@wv1
  g256(stream, y0b, W_A, y_f, nullptr, nullptr, nullptr, 3072, 1536, 1.f,
       x1, W_C, nullptr, v1b, nullptr, nullptr, 4096, 1536, 1.f, 1536, 0);
  // B2: wo1 -> W_A, wo2 -> W_C (pools free after launch1)  [4608 tiles]
  WTB b2{}; b2.NT = 0;
  addop(b2, 0, 13, W_A, 1536, 1536);
  addop(b2, 1, 15, W_C, 1536, 1536);
  finwtb(b2, 2);
  wtransN<<<dim3(b2.NT), dim3(32,8), 0, stream>>>(b2);
  // ln_y
  ln_k<<<3072, 256, 0, stream>>>(y_f, lnyg, lnyb, y1);
  // v2 + q + k  [128 blocks]
  g256_3(stream, y1, wv2T, nullptr, v2b, nullptr, nullptr, 3072, 1536, 1.f,
         x1, W_B, nullptr, qb, nullptr, nullptr, 4096, 512, 0.125f,
         y1, W_B2, nullptr, kbB, nullptr, nullptr, 3072, 512, 1.f, 1536, 0);
  // fused scores ; softmax
  scores_k<<<dim3(12,16,32), 256, 0, stream>>>(qb, kbB, relqb, Tbl, logits);
  softmax_k<<<32768, 256, 0, stream>>>(logits, attnb);
  // transposes for attention GEMMs
  btrans<<<dim3(24,32,32), dim3(32,8), 0, stream>>>(attnb, attnT, 768, 1024,
       8LL*786432, 786432, 8LL*786432, 786432);
  btrans<<<dim3(6,32,32), dim3(32,8), 0, stream>>>(v1b, v1T, 1536, 1024,
       1024LL*1536, 192, 8LL*196608, 196608);
  btrans<<<dim3(6,24,32), dim3(32,8), 0, stream>>>(v2b, v2T, 1536, 768,
       768LL*1536, 192, 8LL*147456, 147456);
  // out1 = attn @ v2 ; out2 = attn^T @ v1
  gemm(stream, attnb, v2T, nullptr, out1, nullptr, nullptr, 1024, 192, 768, 768, 768, 1536,
       32, 8LL*786432, 786432, 8LL*147456, 147456, 1024LL*1536, 192);
  gemm(stream, attnT, v1T, nullptr, out2, nullptr, nullptr, 768, 192, 1024, 1024, 1024, 1536,
       32, 8LL*786432, 786432, 8LL*196608, 196608, 768LL*1536, 192);
  // B3: fy1 -> fy1T, fy2 -> fy2T (uI attn regions dead)  [9216 tiles]
  WTB b3{}; b3.NT = 0;
  addop(b3, 0, 25, fy1T, 1536, 3072);
  addop(b3, 1, 27, fy2T, 3072, 1536);
  finwtb(b3, 2);
  wtransN<<<dim3(b3.NT), dim3(32,8), 0, stream>>>(b3);
  // wo-pair: x4 = x + out1@wo1 + bo1 ; y4 = y + out2@wo2 + bo2
  g256(stream, out1, W_A, x4, nullptr, bo1, x, 4096, 1536, 1.f,
       out2, W_C, y4, nullptr, bo2, y_f, 3072, 1536, 1.f, 1536, 0);
  // FFN LayerNorms
  ln_k<<<4096, 256, 0, stream>>>(x4, fxg, fxbb, x4ln);
  ln_k<<<3072, 256, 0, stream>>>(y4, fyg, fybb, y4ln);
  // ffn1: hidden = relu(ln @ w1 + b1)
  g256(stream, x4ln, W_E, nullptr, hx, fxb1, nullptr, 4096, 3072, 1.f,
       y4ln, fy1T, nullptr, hy, fyb1, nullptr, 3072, 3072, 1.f, 1536, 1);
  // ffn2: out = resid + h @ w2 + b2  (in-place on outx)
  g256(stream, hx, W_F, outx, nullptr, fxb2, x4, 4096, 1536, 1.f,
       hy, fy2T, outy, nullptr, fyb2, y4, 3072, 1536, 1.f, 3072, 0);
}